// Round 1
// baseline (1064.330 us; speedup 1.0000x reference)
//
#include <hip/hip_runtime.h>
#include <hip/hip_bf16.h>

// ---- problem constants ----
#define MOD   3
#define BATCH 65536
#define EDIM  512
#define ADIM  256
#define FEAT  1536   // MOD*EDIM

// ---- types ----
typedef __attribute__((ext_vector_type(8))) short   s16x8;
typedef __attribute__((ext_vector_type(8))) __bf16  bf16x8;
typedef __attribute__((ext_vector_type(4))) float   f32x4;
typedef __attribute__((ext_vector_type(4))) unsigned short u16x4;

__device__ __forceinline__ float b2f(unsigned short u) {
    union { unsigned int ui; float f; } c; c.ui = ((unsigned int)u) << 16; return c.f;
}
__device__ __forceinline__ unsigned short f2b(float f) {
    __hip_bfloat16 h = __float2bfloat16(f);
    return __builtin_bit_cast(unsigned short, h);
}

// ============ kernel 0: x f32 -> bf16 bits ============
__global__ __launch_bounds__(256) void k_convert_x(const float* __restrict__ x,
                                                   unsigned short* __restrict__ xb, int n4) {
    int i = blockIdx.x * blockDim.x + threadIdx.x;
    int stride = gridDim.x * blockDim.x;
    for (; i < n4; i += stride) {
        f32x4 v = *((const f32x4*)x + i);
        u16x4 o;
        for (int j = 0; j < 4; ++j) o[j] = f2b(v[j]);
        *((u16x4*)xb + i) = o;
    }
}

// ============ kernel 1: weight prep (bf16, B-operands pre-transposed to [n][k]) ============
// wqk[m][n][e]  = n<256 ? Wq[m][e][n] : Wk[m][e][n-256]      (3*512*512)
// wtt[p][f][e]  = Wt[p][e][f], p = q*3+k                      (9*512*512)
__global__ __launch_bounds__(256) void k_prep_w(const float* __restrict__ Wq,
                                                const float* __restrict__ Wk,
                                                const float* __restrict__ Wt,
                                                unsigned short* __restrict__ wqk,
                                                unsigned short* __restrict__ wtt) {
    int i = blockIdx.x * blockDim.x + threadIdx.x;
    int stride = gridDim.x * blockDim.x;
    for (int idx = i; idx < MOD * EDIM * EDIM; idx += stride) {
        int m = idx / (EDIM * EDIM); int r = idx % (EDIM * EDIM);
        int n = r / EDIM; int e = r % EDIM;
        float f = (n < ADIM) ? Wq[(m * EDIM + e) * ADIM + n]
                             : Wk[(m * EDIM + e) * ADIM + (n - ADIM)];
        wqk[idx] = f2b(f);
    }
    for (int idx = i; idx < 9 * EDIM * EDIM; idx += stride) {
        int p = idx / (EDIM * EDIM); int r = idx % (EDIM * EDIM);
        int fo = r / EDIM; int e = r % EDIM;
        wtt[idx] = f2b(Wt[((size_t)p * EDIM + e) * EDIM + fo]);
    }
}

// ---- shared GEMM geometry: 128x128 tile, BK=32, 4 waves (2x2), 4x4 frags ----
#define BM  128
#define BN  128
#define BK  32
#define LDT 40   // padded LDS row stride (elements)

// ============ kernel 2: proj = X_m @ [Wq|Wk]_m + bias, bf16 out ============
__global__ __launch_bounds__(256) void k_gemm_proj(const unsigned short* __restrict__ xb,
                                                   const unsigned short* __restrict__ wqk,
                                                   const float* __restrict__ bq,
                                                   const float* __restrict__ bk,
                                                   unsigned short* __restrict__ proj) {
    __shared__ __align__(16) unsigned short As[BM * LDT];
    __shared__ __align__(16) unsigned short Bs[BN * LDT];
    int bid = blockIdx.x;
    int ct = bid & 3, rt = (bid >> 2) & 511, m = bid >> 11;
    int row0 = rt * BM, col0 = ct * BN;
    const unsigned short* Ag = xb  + ((size_t)m * BATCH + row0) * EDIM;
    const unsigned short* Bg = wqk + ((size_t)m * EDIM  + col0) * EDIM;
    int t = threadIdx.x, lane = t & 63, wid = t >> 6;
    int wr = (wid >> 1) * 64, wc = (wid & 1) * 64;
    f32x4 acc[4][4];
    for (int i = 0; i < 4; ++i) for (int j = 0; j < 4; ++j) acc[i][j] = (f32x4)0.f;
    int r0 = t >> 2, kc0 = (t & 3) * 8;
    for (int k0 = 0; k0 < EDIM; k0 += BK) {
        for (int it = 0; it < 2; ++it) {
            int r = r0 + it * 64;
            s16x8 va = *(const s16x8*)(Ag + (size_t)r * EDIM + k0 + kc0);
            *(s16x8*)&As[r * LDT + kc0] = va;
            s16x8 vb = *(const s16x8*)(Bg + (size_t)r * EDIM + k0 + kc0);
            *(s16x8*)&Bs[r * LDT + kc0] = vb;
        }
        __syncthreads();
        int k8 = (lane >> 4) * 8, rr = lane & 15;
        s16x8 af[4], bfr[4];
        for (int i = 0; i < 4; ++i) af[i]  = *(const s16x8*)&As[(wr + i * 16 + rr) * LDT + k8];
        for (int j = 0; j < 4; ++j) bfr[j] = *(const s16x8*)&Bs[(wc + j * 16 + rr) * LDT + k8];
        for (int i = 0; i < 4; ++i)
            for (int j = 0; j < 4; ++j)
                acc[i][j] = __builtin_amdgcn_mfma_f32_16x16x32_bf16(
                    __builtin_bit_cast(bf16x8, af[i]), __builtin_bit_cast(bf16x8, bfr[j]),
                    acc[i][j], 0, 0, 0);
        __syncthreads();
    }
    for (int j = 0; j < 4; ++j) {
        int col = col0 + wc + j * 16 + (lane & 15);
        float bias = (col < ADIM) ? bq[m * ADIM + col] : bk[m * ADIM + col - ADIM];
        for (int i = 0; i < 4; ++i) {
            int rbase = row0 + wr + i * 16 + (lane >> 4) * 4;
            for (int r = 0; r < 4; ++r)
                proj[((size_t)m * BATCH + rbase + r) * EDIM + col] = f2b(acc[i][j][r] + bias);
        }
    }
}

// ============ kernel 3: scores + softmax -> alpha[q][ki][b] (k = (q+1+ki)%3) ============
__global__ __launch_bounds__(256) void k_scores(const unsigned short* __restrict__ proj,
                                                const float* __restrict__ v,
                                                float* __restrict__ alpha) {
    int wid = threadIdx.x >> 6, lane = threadIdx.x & 63;
    size_t b = (size_t)blockIdx.x * 4 + wid;
    float qp[3][4], kp[3][4], vq[3][4];
    for (int m = 0; m < 3; ++m) {
        const unsigned short* p = proj + ((size_t)m * BATCH + b) * EDIM;
        u16x4 uq = *(const u16x4*)(p + lane * 4);
        u16x4 uk = *(const u16x4*)(p + ADIM + lane * 4);
        f32x4 vv = *((const f32x4*)(v + m * ADIM) + lane);
        for (int j = 0; j < 4; ++j) { qp[m][j] = b2f(uq[j]); kp[m][j] = b2f(uk[j]); vq[m][j] = vv[j]; }
    }
    for (int q = 0; q < 3; ++q) {
        float s[2];
        for (int ki = 0; ki < 2; ++ki) {
            int k = (q + 1 + ki) % 3;
            float a = 0.f;
            for (int j = 0; j < 4; ++j) a += vq[q][j] * tanhf(qp[q][j] + kp[k][j]);
            for (int off = 32; off; off >>= 1) a += __shfl_xor(a, off, 64);
            s[ki] = a;
        }
        if (lane == 0) {
            float mx = fmaxf(s[0], s[1]);
            float e0 = expf(s[0] - mx), e1 = expf(s[1] - mx);
            float inv = 1.f / (e0 + e1);
            alpha[(size_t)(q * 2 + 0) * BATCH + b] = e0 * inv;
            alpha[(size_t)(q * 2 + 1) * BATCH + b] = e1 * inv;
        }
    }
}

// ============ kernel 4: att[q] = sum_{k!=q} diag(alpha) * X_k @ Wt[q,k]  (alpha fused in A-staging) ============
__device__ __forceinline__ s16x8 scale8(s16x8 vv, float a) {
    s16x8 o;
    for (int j = 0; j < 8; ++j) o[j] = (short)f2b(b2f((unsigned short)vv[j]) * a);
    return o;
}

__global__ __launch_bounds__(256) void k_gemm_att(const unsigned short* __restrict__ xb,
                                                  const unsigned short* __restrict__ wtt,
                                                  const float* __restrict__ alpha,
                                                  unsigned short* __restrict__ att) {
    __shared__ __align__(16) unsigned short As[BM * LDT];
    __shared__ __align__(16) unsigned short Bs[BN * LDT];
    int bid = blockIdx.x;
    int ct = bid & 3, rt = (bid >> 2) & 511, q = bid >> 11;
    int row0 = rt * BM, col0 = ct * BN;
    int t = threadIdx.x, lane = t & 63, wid = t >> 6;
    int wr = (wid >> 1) * 64, wc = (wid & 1) * 64;
    f32x4 acc[4][4];
    for (int i = 0; i < 4; ++i) for (int j = 0; j < 4; ++j) acc[i][j] = (f32x4)0.f;
    int r0 = t >> 2, kc0 = (t & 3) * 8;
    for (int ki = 0; ki < 2; ++ki) {
        int k = (q + 1 + ki) % 3;
        const unsigned short* Ag = xb  + ((size_t)k * BATCH + row0) * EDIM;
        const unsigned short* Bg = wtt + ((size_t)(q * 3 + k) * EDIM + col0) * EDIM;
        const float* al = alpha + (size_t)(q * 2 + ki) * BATCH + row0;
        float a0 = al[r0], a1 = al[r0 + 64];
        for (int k0 = 0; k0 < EDIM; k0 += BK) {
            s16x8 va0 = *(const s16x8*)(Ag + (size_t)r0 * EDIM + k0 + kc0);
            *(s16x8*)&As[r0 * LDT + kc0] = scale8(va0, a0);
            s16x8 va1 = *(const s16x8*)(Ag + (size_t)(r0 + 64) * EDIM + k0 + kc0);
            *(s16x8*)&As[(r0 + 64) * LDT + kc0] = scale8(va1, a1);
            s16x8 vb0 = *(const s16x8*)(Bg + (size_t)r0 * EDIM + k0 + kc0);
            *(s16x8*)&Bs[r0 * LDT + kc0] = vb0;
            s16x8 vb1 = *(const s16x8*)(Bg + (size_t)(r0 + 64) * EDIM + k0 + kc0);
            *(s16x8*)&Bs[(r0 + 64) * LDT + kc0] = vb1;
            __syncthreads();
            int k8 = (lane >> 4) * 8, rr = lane & 15;
            s16x8 af[4], bfr[4];
            for (int i = 0; i < 4; ++i) af[i]  = *(const s16x8*)&As[(wr + i * 16 + rr) * LDT + k8];
            for (int j = 0; j < 4; ++j) bfr[j] = *(const s16x8*)&Bs[(wc + j * 16 + rr) * LDT + k8];
            for (int i = 0; i < 4; ++i)
                for (int j = 0; j < 4; ++j)
                    acc[i][j] = __builtin_amdgcn_mfma_f32_16x16x32_bf16(
                        __builtin_bit_cast(bf16x8, af[i]), __builtin_bit_cast(bf16x8, bfr[j]),
                        acc[i][j], 0, 0, 0);
            __syncthreads();
        }
    }
    for (int j = 0; j < 4; ++j) {
        int col = col0 + wc + j * 16 + (lane & 15);
        for (int i = 0; i < 4; ++i) {
            int rbase = row0 + wr + i * 16 + (lane >> 4) * 4;
            for (int r = 0; r < 4; ++r)
                att[((size_t)q * BATCH + rbase + r) * EDIM + col] = f2b(acc[i][j][r]);
        }
    }
}

// ============ kernel 5: out = LN(x + att + sum_k alpha*bt) ============
__global__ __launch_bounds__(512) void k_fuse_ln(const float* __restrict__ x,
                                                 const unsigned short* __restrict__ att,
                                                 const float* __restrict__ alpha,
                                                 const float* __restrict__ bt,
                                                 const float* __restrict__ gamma,
                                                 const float* __restrict__ beta,
                                                 float* __restrict__ out) {
    __shared__ float red[2][8];
    int b = blockIdx.x, t = threadIdx.x;
    int lane = t & 63, w = t >> 6;
    float val[3], s = 0.f, s2 = 0.f;
    for (int m = 0; m < 3; ++m) {
        float a0 = alpha[(size_t)(m * 2 + 0) * BATCH + b];
        float a1 = alpha[(size_t)(m * 2 + 1) * BATCH + b];
        int kA = (m + 1) % 3, kB = (m + 2) % 3;
        float bias = a0 * bt[(m * 3 + kA) * EDIM + t] + a1 * bt[(m * 3 + kB) * EDIM + t];
        size_t off = ((size_t)m * BATCH + b) * EDIM + t;
        float vv = x[off] + b2f(att[off]) + bias;
        val[m] = vv; s += vv; s2 += vv * vv;
    }
    for (int off = 32; off; off >>= 1) { s += __shfl_xor(s, off, 64); s2 += __shfl_xor(s2, off, 64); }
    if (lane == 0) { red[0][w] = s; red[1][w] = s2; }
    __syncthreads();
    float S = 0.f, S2 = 0.f;
    for (int i = 0; i < 8; ++i) { S += red[0][i]; S2 += red[1][i]; }
    float mu  = S * (1.f / 1536.f);
    float var = S2 * (1.f / 1536.f) - mu * mu;
    float rs  = rsqrtf(var + 1e-5f);
    for (int m = 0; m < 3; ++m) {
        int f = m * EDIM + t;
        out[(size_t)b * FEAT + f] = (val[m] - mu) * rs * gamma[f] + beta[f];
    }
}

// ============ launcher ============
extern "C" void kernel_launch(void* const* d_in, const int* in_sizes, int n_in,
                              void* d_out, int out_size, void* d_ws, size_t ws_size,
                              hipStream_t stream) {
    const float* x     = (const float*)d_in[0];
    const float* Wq    = (const float*)d_in[1];
    const float* bq    = (const float*)d_in[2];
    const float* Wk    = (const float*)d_in[3];
    const float* bk    = (const float*)d_in[4];
    const float* v     = (const float*)d_in[5];
    const float* Wt    = (const float*)d_in[6];
    const float* bt    = (const float*)d_in[7];
    const float* gamma = (const float*)d_in[8];
    const float* beta  = (const float*)d_in[9];
    float* out = (float*)d_out;

    char* ws = (char*)d_ws;
    unsigned short* xb   = (unsigned short*)(ws);                 // 192 MiB
    unsigned short* proj = (unsigned short*)(ws + 201326592);     // 192 MiB (reused as att)
    unsigned short* wqk  = (unsigned short*)(ws + 402653184);     // 1.5 MiB
    unsigned short* wtt  = (unsigned short*)(ws + 404226048);     // 4.5 MiB
    float*          alpha= (float*)        (ws + 408944640);      // 1.5 MiB

    k_convert_x<<<4096, 256, 0, stream>>>(x, xb, (MOD * BATCH * EDIM) / 4);
    k_prep_w  <<<2048, 256, 0, stream>>>(Wq, Wk, Wt, wqk, wtt);
    k_gemm_proj<<<6144, 256, 0, stream>>>(xb, wqk, bq, bk, proj);
    k_scores  <<<16384, 256, 0, stream>>>(proj, v, alpha);
    k_gemm_att<<<6144, 256, 0, stream>>>(xb, wtt, alpha, proj /* att aliases proj */);
    k_fuse_ln <<<65536, 512, 0, stream>>>(x, proj, alpha, bt, gamma, beta, out);
}

// Round 2
// 912.518 us; speedup vs baseline: 1.1664x; 1.1664x over previous
//
#include <hip/hip_runtime.h>
#include <hip/hip_bf16.h>

// ---- problem constants ----
#define MOD   3
#define BATCH 65536
#define EDIM  512
#define ADIM  256
#define FEAT  1536   // MOD*EDIM

// ---- types ----
typedef __attribute__((ext_vector_type(8))) short   s16x8;
typedef __attribute__((ext_vector_type(8))) __bf16  bf16x8;
typedef __attribute__((ext_vector_type(4))) float   f32x4;
typedef __attribute__((ext_vector_type(4))) unsigned short u16x4;

__device__ __forceinline__ float b2f(unsigned short u) {
    union { unsigned int ui; float f; } c; c.ui = ((unsigned int)u) << 16; return c.f;
}
__device__ __forceinline__ unsigned short f2b(float f) {
    __hip_bfloat16 h = __float2bfloat16(f);
    return __builtin_bit_cast(unsigned short, h);
}

// async global->LDS, 16B per lane (wave-uniform LDS base + lane*16)
__device__ __forceinline__ void glds16(const unsigned short* g, unsigned short* l) {
    __builtin_amdgcn_global_load_lds(
        (const __attribute__((address_space(1))) void*)g,
        (__attribute__((address_space(3))) void*)l, 16, 0, 0);
}

// ============ kernel 0: x f32 -> bf16 bits ============
__global__ __launch_bounds__(256) void k_convert_x(const float* __restrict__ x,
                                                   unsigned short* __restrict__ xb, int n4) {
    int i = blockIdx.x * blockDim.x + threadIdx.x;
    int stride = gridDim.x * blockDim.x;
    for (; i < n4; i += stride) {
        f32x4 v = *((const f32x4*)x + i);
        u16x4 o;
        for (int j = 0; j < 4; ++j) o[j] = f2b(v[j]);
        *((u16x4*)xb + i) = o;
    }
}

// ============ kernel 1: weight prep ============
// wqk [m][n][e]   n<256 -> Wq[m][e][n] else Wk[m][e][n-256]      (3*512*512)
// wtt2[k][n][e]   n<512 -> Wt[(k+1)%3][k][e][n]  (pair ki=1 of q=(k+1)%3)
//                 n>=512-> Wt[(k+2)%3][k][e][n-512] (pair ki=0 of q=(k+2)%3)
__global__ __launch_bounds__(256) void k_prep_w(const float* __restrict__ Wq,
                                                const float* __restrict__ Wk,
                                                const float* __restrict__ Wt,
                                                unsigned short* __restrict__ wqk,
                                                unsigned short* __restrict__ wtt2) {
    int i = blockIdx.x * blockDim.x + threadIdx.x;
    int stride = gridDim.x * blockDim.x;
    for (int idx = i; idx < MOD * EDIM * EDIM; idx += stride) {
        int m = idx / (EDIM * EDIM); int r = idx % (EDIM * EDIM);
        int n = r / EDIM; int e = r % EDIM;
        float f = (n < ADIM) ? Wq[(m * EDIM + e) * ADIM + n]
                             : Wk[(m * EDIM + e) * ADIM + (n - ADIM)];
        wqk[idx] = f2b(f);
    }
    for (int idx = i; idx < MOD * 1024 * EDIM; idx += stride) {
        int k = idx / (1024 * EDIM); int r = idx % (1024 * EDIM);
        int n = r / EDIM; int e = r % EDIM;
        int q = (n < EDIM) ? (k + 1) % 3 : (k + 2) % 3;
        int f = (n < EDIM) ? n : n - EDIM;
        wtt2[idx] = f2b(Wt[((size_t)(q * 3 + k) * EDIM + e) * EDIM + f]);
    }
}

// ---- shared GEMM geometry: 128x128 tile, BK=32, 4 waves (2x2), 4x4 frags ----
#define BM  128
#define BN  128
#define BK  32

__device__ __forceinline__ int swz4(int row) { return (row ^ (row >> 2)) & 3; }

// Core K=512 loop: linear LDS tiles [128][32] bf16, XOR-swizzled 16B groups.
// global_load_lds writes linearly; the global SOURCE is pre-swizzled so that
// LDS[row][g] holds global col-group g ^ swz4(row); reads apply the same XOR.
__device__ __forceinline__ void gemm_k512(const unsigned short* __restrict__ Ag,
                                          const unsigned short* __restrict__ Bg,
                                          unsigned short* __restrict__ As,
                                          unsigned short* __restrict__ Bs,
                                          f32x4 (&acc)[4][4]) {
    const int t = threadIdx.x, lane = t & 63, wid = t >> 6;
    const int wr = (wid >> 1) * 64, wc = (wid & 1) * 64;

    // ---- staging: wave w covers rows [w*16,w*16+16) (round 0) and +64 (round 1)
    const int r0 = wid * 16 + (lane >> 2);
    const int r1 = r0 + 64;
    const int g0 = (lane & 3) ^ swz4(r0);
    const int g1 = (lane & 3) ^ swz4(r1);
    const unsigned short* gA0 = Ag + (size_t)r0 * EDIM + g0 * 8;
    const unsigned short* gA1 = Ag + (size_t)r1 * EDIM + g1 * 8;
    const unsigned short* gB0 = Bg + (size_t)r0 * EDIM + g0 * 8;
    const unsigned short* gB1 = Bg + (size_t)r1 * EDIM + g1 * 8;
    unsigned short* lA0 = As + wid * 512;          // bytes: wid*1024
    unsigned short* lA1 = As + 2048 + wid * 512;   // second 4KB half
    unsigned short* lB0 = Bs + wid * 512;
    unsigned short* lB1 = Bs + 2048 + wid * 512;

    // ---- fragment read addresses (constant across K-steps)
    const int rr = lane & 15, cg = lane >> 4;
    const unsigned short* aAdr[4];
    const unsigned short* bAdr[4];
#pragma unroll
    for (int i = 0; i < 4; ++i) {
        int ra = wr + i * 16 + rr;
        aAdr[i] = As + ra * BK + ((cg ^ swz4(ra)) * 8);
        int rb = wc + i * 16 + rr;
        bAdr[i] = Bs + rb * BK + ((cg ^ swz4(rb)) * 8);
    }

    for (int kk = 0; kk < EDIM / BK; ++kk) {
        glds16(gA0, lA0); glds16(gA1, lA1);
        glds16(gB0, lB0); glds16(gB1, lB1);
        gA0 += BK; gA1 += BK; gB0 += BK; gB1 += BK;
        __syncthreads();                       // vmcnt(0) drain + barrier
        s16x8 af[4], bfr[4];
#pragma unroll
        for (int i = 0; i < 4; ++i) af[i]  = *(const s16x8*)aAdr[i];
#pragma unroll
        for (int j = 0; j < 4; ++j) bfr[j] = *(const s16x8*)bAdr[j];
#pragma unroll
        for (int i = 0; i < 4; ++i)
#pragma unroll
            for (int j = 0; j < 4; ++j)
                acc[i][j] = __builtin_amdgcn_mfma_f32_16x16x32_bf16(
                    __builtin_bit_cast(bf16x8, af[i]), __builtin_bit_cast(bf16x8, bfr[j]),
                    acc[i][j], 0, 0, 0);
        __syncthreads();                       // protect LDS for next stage
    }
}

// ============ kernel 2: proj = X_m @ [Wq|Wk]_m + bias, bf16 out ============
__global__ __launch_bounds__(256) void k_gemm_proj(const unsigned short* __restrict__ xb,
                                                   const unsigned short* __restrict__ wqk,
                                                   const float* __restrict__ bq,
                                                   const float* __restrict__ bk,
                                                   unsigned short* __restrict__ proj) {
    __shared__ __align__(16) unsigned short As[BM * BK];
    __shared__ __align__(16) unsigned short Bs[BN * BK];
    // XCD-chunked swizzle: nwg = 6144, 768 per XCD
    int l = (blockIdx.x & 7) * 768 + (blockIdx.x >> 3);
    int ct = l & 3, rt = (l >> 2) & 511, m = l >> 11;
    int row0 = rt * BM, col0 = ct * BN;
    f32x4 acc[4][4];
#pragma unroll
    for (int i = 0; i < 4; ++i) for (int j = 0; j < 4; ++j) acc[i][j] = (f32x4)0.f;
    gemm_k512(xb + ((size_t)m * BATCH + row0) * EDIM,
              wqk + ((size_t)m * EDIM + col0) * EDIM, As, Bs, acc);
    int lane = threadIdx.x & 63, wid = threadIdx.x >> 6;
    int wr = (wid >> 1) * 64, wc = (wid & 1) * 64;
#pragma unroll
    for (int j = 0; j < 4; ++j) {
        int col = col0 + wc + j * 16 + (lane & 15);
        float bias = (col < ADIM) ? bq[m * ADIM + col] : bk[m * ADIM + col - ADIM];
#pragma unroll
        for (int i = 0; i < 4; ++i) {
            int rbase = row0 + wr + i * 16 + (lane >> 4) * 4;
#pragma unroll
            for (int r = 0; r < 4; ++r)
                proj[((size_t)m * BATCH + rbase + r) * EDIM + col] = f2b(acc[i][j][r] + bias);
        }
    }
}

// ============ kernel 3: scores + softmax -> alpha[q*2+ki][b], k=(q+1+ki)%3 ============
__global__ __launch_bounds__(256) void k_scores(const unsigned short* __restrict__ proj,
                                                const float* __restrict__ v,
                                                float* __restrict__ alpha) {
    int wid = threadIdx.x >> 6, lane = threadIdx.x & 63;
    size_t b = (size_t)blockIdx.x * 4 + wid;
    float qp[3][4], kp[3][4], vq[3][4];
    for (int m = 0; m < 3; ++m) {
        const unsigned short* p = proj + ((size_t)m * BATCH + b) * EDIM;
        u16x4 uq = *(const u16x4*)(p + lane * 4);
        u16x4 uk = *(const u16x4*)(p + ADIM + lane * 4);
        f32x4 vv = *((const f32x4*)(v + m * ADIM) + lane);
        for (int j = 0; j < 4; ++j) { qp[m][j] = b2f(uq[j]); kp[m][j] = b2f(uk[j]); vq[m][j] = vv[j]; }
    }
    for (int q = 0; q < 3; ++q) {
        float s[2];
        for (int ki = 0; ki < 2; ++ki) {
            int k = (q + 1 + ki) % 3;
            float a = 0.f;
            for (int j = 0; j < 4; ++j) a += vq[q][j] * tanhf(qp[q][j] + kp[k][j]);
            for (int off = 32; off; off >>= 1) a += __shfl_xor(a, off, 64);
            s[ki] = a;
        }
        if (lane == 0) {
            float mx = fmaxf(s[0], s[1]);
            float e0 = expf(s[0] - mx), e1 = expf(s[1] - mx);
            float inv = 1.f / (e0 + e1);
            alpha[(size_t)(q * 2 + 0) * BATCH + b] = e0 * inv;
            alpha[(size_t)(q * 2 + 1) * BATCH + b] = e1 * inv;
        }
    }
}

// ============ kernel 4: Y[k] = X_k @ wtt2[k]  (N=1024, pure GEMM, alpha deferred) ============
__global__ __launch_bounds__(256) void k_gemm_y(const unsigned short* __restrict__ xb,
                                                const unsigned short* __restrict__ wtt2,
                                                unsigned short* __restrict__ y) {
    __shared__ __align__(16) unsigned short As[BM * BK];
    __shared__ __align__(16) unsigned short Bs[BN * BK];
    // XCD-chunked swizzle: nwg = 12288, 1536 per XCD
    int l = (blockIdx.x & 7) * 1536 + (blockIdx.x >> 3);
    int ct = l & 7, rt = (l >> 3) & 511, k = l >> 12;
    int row0 = rt * BM, col0 = ct * BN;
    f32x4 acc[4][4];
#pragma unroll
    for (int i = 0; i < 4; ++i) for (int j = 0; j < 4; ++j) acc[i][j] = (f32x4)0.f;
    gemm_k512(xb  + ((size_t)k * BATCH + row0) * EDIM,
              wtt2 + ((size_t)k * 1024 + col0) * EDIM, As, Bs, acc);
    int lane = threadIdx.x & 63, wid = threadIdx.x >> 6;
    int wr = (wid >> 1) * 64, wc = (wid & 1) * 64;
    // pair index: ct<4 -> (q=(k+1)%3, ki=1); ct>=4 -> (q=(k+2)%3, ki=0)
    int p   = (ct < 4) ? (((k + 1) % 3) * 2 + 1) : (((k + 2) % 3) * 2 + 0);
    int cb  = (ct < 4) ? col0 : (col0 - EDIM);
#pragma unroll
    for (int j = 0; j < 4; ++j) {
        int col = cb + wc + j * 16 + (lane & 15);
#pragma unroll
        for (int i = 0; i < 4; ++i) {
            int rbase = row0 + wr + i * 16 + (lane >> 4) * 4;
#pragma unroll
            for (int r = 0; r < 4; ++r)
                y[((size_t)p * BATCH + rbase + r) * EDIM + col] = f2b(acc[i][j][r]);
        }
    }
}

// ============ kernel 5: out = LN(x + a0*(Y0+bt0) + a1*(Y1+bt1)) ============
__global__ __launch_bounds__(192) void k_fuse_ln(const float* __restrict__ x,
                                                 const unsigned short* __restrict__ y,
                                                 const float* __restrict__ alpha,
                                                 const float* __restrict__ bt,
                                                 const float* __restrict__ gamma,
                                                 const float* __restrict__ beta,
                                                 float* __restrict__ out) {
    __shared__ float red[2][3];
    int b = blockIdx.x, t = threadIdx.x, m = t >> 6, lane = t & 63;
    int e0 = lane * 8;
    float a0 = alpha[(size_t)(m * 2 + 0) * BATCH + b];
    float a1 = alpha[(size_t)(m * 2 + 1) * BATCH + b];
    const float* xp = x + ((size_t)m * BATCH + b) * EDIM + e0;
    f32x4 xv0 = *(const f32x4*)xp, xv1 = *(const f32x4*)(xp + 4);
    s16x8 y0 = *(const s16x8*)(y + ((size_t)(m * 2 + 0) * BATCH + b) * EDIM + e0);
    s16x8 y1 = *(const s16x8*)(y + ((size_t)(m * 2 + 1) * BATCH + b) * EDIM + e0);
    int kA = (m + 1) % 3, kB = (m + 2) % 3;
    const float* bA = bt + (size_t)(m * 3 + kA) * EDIM + e0;
    const float* bB = bt + (size_t)(m * 3 + kB) * EDIM + e0;
    f32x4 bA0 = *(const f32x4*)bA, bA1 = *(const f32x4*)(bA + 4);
    f32x4 bB0 = *(const f32x4*)bB, bB1 = *(const f32x4*)(bB + 4);
    float v[8]; float s = 0.f, s2 = 0.f;
#pragma unroll
    for (int j = 0; j < 8; ++j) {
        float xx = (j < 4) ? xv0[j] : xv1[j - 4];
        float ba = (j < 4) ? bA0[j] : bA1[j - 4];
        float bb = (j < 4) ? bB0[j] : bB1[j - 4];
        float vv = xx + a0 * (b2f((unsigned short)y0[j]) + ba)
                      + a1 * (b2f((unsigned short)y1[j]) + bb);
        v[j] = vv; s += vv; s2 += vv * vv;
    }
    for (int off = 32; off; off >>= 1) { s += __shfl_xor(s, off, 64); s2 += __shfl_xor(s2, off, 64); }
    if (lane == 0) { red[0][m] = s; red[1][m] = s2; }
    __syncthreads();
    float S = red[0][0] + red[0][1] + red[0][2];
    float S2 = red[1][0] + red[1][1] + red[1][2];
    float mu  = S * (1.f / 1536.f);
    float var = S2 * (1.f / 1536.f) - mu * mu;
    float rs  = rsqrtf(var + 1e-5f);
    int f0 = m * EDIM + e0;
    f32x4 g0 = *(const f32x4*)(gamma + f0), g1 = *(const f32x4*)(gamma + f0 + 4);
    f32x4 be0 = *(const f32x4*)(beta + f0), be1 = *(const f32x4*)(beta + f0 + 4);
    f32x4 o0, o1;
#pragma unroll
    for (int j = 0; j < 4; ++j) {
        o0[j] = (v[j]     - mu) * rs * g0[j] + be0[j];
        o1[j] = (v[j + 4] - mu) * rs * g1[j] + be1[j];
    }
    float* op = out + (size_t)b * FEAT + f0;
    *(f32x4*)op = o0; *(f32x4*)(op + 4) = o1;
}

// ============ launcher ============
extern "C" void kernel_launch(void* const* d_in, const int* in_sizes, int n_in,
                              void* d_out, int out_size, void* d_ws, size_t ws_size,
                              hipStream_t stream) {
    const float* x     = (const float*)d_in[0];
    const float* Wq    = (const float*)d_in[1];
    const float* bq    = (const float*)d_in[2];
    const float* Wk    = (const float*)d_in[3];
    const float* bk    = (const float*)d_in[4];
    const float* v     = (const float*)d_in[5];
    const float* Wt    = (const float*)d_in[6];
    const float* bt    = (const float*)d_in[7];
    const float* gamma = (const float*)d_in[8];
    const float* beta  = (const float*)d_in[9];
    float* out = (float*)d_out;

    char* ws = (char*)d_ws;
    // layout (bytes):
    //   [0,            1572864)   wqk   bf16 3*512*512
    //   [1572864,      4718592)   wtt2  bf16 3*1024*512
    //   [4718592,      6291456)   alpha f32  6*65536
    //   [6291456,    207618048)   xb    bf16 3*65536*512
    //   [207618048,  610271232)   y     bf16 6*65536*512   (proj aliases first half)
    unsigned short* wqk   = (unsigned short*)(ws);
    unsigned short* wtt2  = (unsigned short*)(ws + 1572864);
    float*          alpha = (float*)        (ws + 4718592);
    unsigned short* xb    = (unsigned short*)(ws + 6291456);
    unsigned short* y     = (unsigned short*)(ws + 207618048);
    unsigned short* proj  = y;  // alias: proj fully consumed by k_scores before k_gemm_y writes y

    k_convert_x<<<4096, 256, 0, stream>>>(x, xb, (MOD * BATCH * EDIM) / 4);
    k_prep_w   <<<2048, 256, 0, stream>>>(Wq, Wk, Wt, wqk, wtt2);
    k_gemm_proj<<<6144, 256, 0, stream>>>(xb, wqk, bq, bk, proj);
    k_scores   <<<16384, 256, 0, stream>>>(proj, v, alpha);
    k_gemm_y   <<<12288, 256, 0, stream>>>(xb, wtt2, y);
    k_fuse_ln  <<<65536, 192, 0, stream>>>(x, y, alpha, bt, gamma, beta, out);
}